// Round 1
// baseline (96.452 us; speedup 1.0000x reference)
//
#include <hip/hip_runtime.h>
#include <hip/hip_bf16.h>

// Problem constants: feature [B=128, E=64, D=128] fp32 -> N = 8192 rows of dim 128.
#define N_ROWS 8192
#define DIM    128
#define TILE   128
#define PADH   136   // LDS halfwords per row: 128 + 8 pad (16B) -> 2-way bank alias max (free)
#define CPG    8     // col tiles per block
#define EXPTEN 22026.465794806718f  // exp(10.0)

typedef __attribute__((ext_vector_type(8))) short short8;   // 8 bf16 = 4 VGPRs
typedef __attribute__((ext_vector_type(4))) float floatx4;  // MFMA C/D

// ---------------- Kernel 1: L2-normalize rows, cast to bf16 ----------------
__global__ void norm_kernel(const float* __restrict__ F, __hip_bfloat16* __restrict__ Xb) {
    int lane = threadIdx.x & 63;
    int wave = threadIdx.x >> 6;
    int row  = blockIdx.x * 4 + wave;           // grid = 2048 blocks of 4 waves
    const float2 v = *(const float2*)(F + (size_t)row * DIM + lane * 2);
    float ss = v.x * v.x + v.y * v.y;
    #pragma unroll
    for (int m = 1; m < 64; m <<= 1) ss += __shfl_xor(ss, m);
    float inv = rsqrtf(ss);
    __hip_bfloat162 o;
    o.x = __float2bfloat16(v.x * inv);
    o.y = __float2bfloat16(v.y * inv);
    *((__hip_bfloat162*)(Xb + (size_t)row * DIM) + lane) = o;
}

// ---------------- Kernel 2: fused gram + exp + row sums ----------------
// Block (rb, cg): rows [rb*128, rb*128+128), cols ct in {cg*8 .. cg*8+7} tiles of 128.
// 4 waves in 2x2; wave (wm, wn) owns a 64x64 subtile. 16x16x32 bf16 MFMA, K=128.
__global__ __launch_bounds__(256, 2) void gram_kernel(
        const __hip_bfloat16* __restrict__ Xb,
        float* __restrict__ pos, float* __restrict__ den) {
    __shared__ __hip_bfloat16 As[TILE * PADH];
    __shared__ __hip_bfloat16 Bs[TILE * PADH];
    const int tid  = threadIdx.x;
    const int rb   = blockIdx.x;      // 0..63
    const int cg   = blockIdx.y;      // 0..7
    const int lane = tid & 63;
    const int wave = tid >> 6;
    const int wm   = wave >> 1, wn = wave & 1;
    const int quad = lane >> 4;       // 0..3
    const int l15  = lane & 15;       // 0..15

    // Load A tile (rows rb*128..): 128x128 bf16, 16B chunks, 8 iters x 256 threads.
    #pragma unroll
    for (int it = 0; it < 8; ++it) {
        int idx = it * 256 + tid;         // 0..2047
        int row = idx >> 4, c8 = idx & 15;
        float4 t = *(const float4*)(Xb + ((size_t)(rb * TILE + row)) * DIM + c8 * 8);
        *(float4*)((char*)As + row * (PADH * 2) + c8 * 16) = t;
    }

    float dp[4][4], pp[4][4];
    #pragma unroll
    for (int a = 0; a < 4; ++a)
        #pragma unroll
        for (int b = 0; b < 4; ++b) { dp[a][b] = 0.f; pp[a][b] = 0.f; }

    for (int t = 0; t < CPG; ++t) {
        const int ct = cg * CPG + t;
        __syncthreads();   // waves done reading Bs (and As on t==0 done writing)
        #pragma unroll
        for (int it = 0; it < 8; ++it) {
            int idx = it * 256 + tid;
            int row = idx >> 4, c8 = idx & 15;
            float4 v = *(const float4*)(Xb + ((size_t)(ct * TILE + row)) * DIM + c8 * 8);
            *(float4*)((char*)Bs + row * (PADH * 2) + c8 * 16) = v;
        }
        __syncthreads();

        floatx4 acc[4][4];
        #pragma unroll
        for (int mi = 0; mi < 4; ++mi)
            #pragma unroll
            for (int ni = 0; ni < 4; ++ni) acc[mi][ni] = (floatx4)0.0f;

        #pragma unroll
        for (int ko = 0; ko < 4; ++ko) {
            short8 af[4], bf[4];
            #pragma unroll
            for (int mi = 0; mi < 4; ++mi) {
                int r = wm * 64 + mi * 16 + l15;
                af[mi] = *(const short8*)((const char*)As + r * (PADH * 2) + ko * 64 + quad * 16);
            }
            #pragma unroll
            for (int ni = 0; ni < 4; ++ni) {
                int r = wn * 64 + ni * 16 + l15;
                bf[ni] = *(const short8*)((const char*)Bs + r * (PADH * 2) + ko * 64 + quad * 16);
            }
            #pragma unroll
            for (int mi = 0; mi < 4; ++mi)
                #pragma unroll
                for (int ni = 0; ni < 4; ++ni)
                    acc[mi][ni] = __builtin_amdgcn_mfma_f32_16x16x32_bf16(
                        af[mi], bf[ni], acc[mi][ni], 0, 0, 0);
        }

        // Fused epilogue. is_pos / is_diag are wave-uniform per tile:
        //   grow>>6 = rb*2+wm (uniform), gcol>>6 = ct*2+wn (uniform).
        const bool pos_tile = (ct == rb) && (wm == wn);
        #pragma unroll
        for (int mi = 0; mi < 4; ++mi)
            #pragma unroll
            for (int rg = 0; rg < 4; ++rg) {
                float dadd = 0.f;
                #pragma unroll
                for (int ni = 0; ni < 4; ++ni)
                    dadd += __expf(acc[mi][ni][rg] * 10.0f);
                if (pos_tile) {
                    // diagonal element: ni==mi fragment, col l15 == row quad*4+rg.
                    // Replace bf16-noisy exp(10*||x||^2) with exact exp(10).
                    if (l15 == quad * 4 + rg)
                        dadd += EXPTEN - __expf(acc[mi][mi][rg] * 10.0f);
                    pp[mi][rg] += dadd;
                }
                dp[mi][rg] += dadd;
            }
    }

    // Reduce across the 16 lanes of each quad-group (cols), then atomics per row.
    const bool has_pos = (wm == wn) && ((rb >> 3) == cg);
    #pragma unroll
    for (int mi = 0; mi < 4; ++mi)
        #pragma unroll
        for (int rg = 0; rg < 4; ++rg) {
            float d = dp[mi][rg];
            #pragma unroll
            for (int m = 1; m < 16; m <<= 1) d += __shfl_xor(d, m);
            int grow = rb * TILE + wm * 64 + mi * 16 + quad * 4 + rg;
            if (l15 == 0) atomicAdd(&den[grow], d);
            if (has_pos) {
                float p = pp[mi][rg];
                #pragma unroll
                for (int m = 1; m < 16; m <<= 1) p += __shfl_xor(p, m);
                if (l15 == 0) atomicAdd(&pos[grow], p);
            }
        }
}

// ---------------- Kernel 3: loss = mean(log(den/pos)) ----------------
__global__ void loss_kernel(const float* __restrict__ pos, const float* __restrict__ den,
                            float* __restrict__ out) {
    __shared__ float red[4];
    float acc = 0.f;
    for (int r = threadIdx.x; r < N_ROWS; r += 256)
        acc += __logf(den[r] / pos[r]);
    #pragma unroll
    for (int m = 1; m < 64; m <<= 1) acc += __shfl_xor(acc, m);
    int lane = threadIdx.x & 63, w = threadIdx.x >> 6;
    if (lane == 0) red[w] = acc;
    __syncthreads();
    if (threadIdx.x == 0)
        out[0] = (red[0] + red[1] + red[2] + red[3]) * (1.0f / (float)N_ROWS);
}

extern "C" void kernel_launch(void* const* d_in, const int* in_sizes, int n_in,
                              void* d_out, int out_size, void* d_ws, size_t ws_size,
                              hipStream_t stream) {
    const float* feature = (const float*)d_in[0];
    // ws layout: pos[8192] f32 | den[8192] f32 | Xb[8192*128] bf16  (~2.06 MB total)
    float* pos = (float*)d_ws;
    float* den = pos + N_ROWS;
    __hip_bfloat16* Xb = (__hip_bfloat16*)(den + N_ROWS);

    hipMemsetAsync(d_ws, 0, 2 * N_ROWS * sizeof(float), stream);
    norm_kernel<<<N_ROWS / 4, 256, 0, stream>>>(feature, Xb);
    gram_kernel<<<dim3(64, 8), 256, 0, stream>>>(Xb, pos, den);
    loss_kernel<<<1, 256, 0, stream>>>(pos, den, (float*)d_out);
}